// Round 4
// baseline (2530.243 us; speedup 1.0000x reference)
//
#include <hip/hip_runtime.h>
#include <hip/hip_bf16.h>
#include <math.h>

// ---------------- problem constants ----------------
#define D        256
#define NINNER   2048
#define NROW     2049          // 2048 + dustbin
#define SP       2064          // padded row stride (floats), 16B-aligned rows
#define ITERS_N  100
#define EPS_F    0.8f
#define TAU_F    1.02f
#define NB       256           // persistent blocks
#define NT       256           // threads per block

// ws layout (in floats)
#define OFF_E    0u
#define SZ_MAT   (2049u * 2064u)          // 4229136
#define OFF_F    (OFF_E + SZ_MAT)
#define OFF_WU   (OFF_F + SZ_MAT)
#define OFF_WV   (OFF_WU + 2176u)
#define OFF_BAR  (OFF_WV + 2176u)         // 256 per-block epoch flags (monotone)
#define OFF_MAX0 (OFF_BAR + 4096u)
#define OFF_IDX0 (OFF_MAX0 + 2048u)
#define OFF_IDX1 (OFF_IDX0 + 2048u)
#define OFF_MS0  (OFF_IDX1 + 2048u)
#define OFF_VLD0 (OFF_MS0 + 2048u)

// d_out layout (floats)
#define OOFF_Z   0u
#define OOFF_I0  (2049u * 2049u)          // 4198401
#define OOFF_I1  (OOFF_I0 + 2048u)
#define OOFF_S0  (OOFF_I1 + 2048u)
#define OOFF_S1  (OOFF_S0 + 2048u)

// ---------------- K1: fp32 GEMM -> E = exp(scores) ----------------
__global__ __launch_bounds__(256) void k_gemm(const float* __restrict__ A,
                                              const float* __restrict__ Bm,
                                              float* __restrict__ E) {
    __shared__ float As[8][64];
    __shared__ float Bs[8][64];
    const int tid = threadIdx.x;
    const int tx = tid & 15, ty = tid >> 4;
    const int row0 = blockIdx.y * 64, col0 = blockIdx.x * 64;
    float acc[4][4] = {};
    const int lr = tid >> 6, lc = tid & 63;
    for (int k0 = 0; k0 < D; k0 += 8) {
        As[lr][lc]     = A[(k0 + lr) * NINNER + row0 + lc];
        As[lr + 4][lc] = A[(k0 + lr + 4) * NINNER + row0 + lc];
        Bs[lr][lc]     = Bm[(k0 + lr) * NINNER + col0 + lc];
        Bs[lr + 4][lc] = Bm[(k0 + lr + 4) * NINNER + col0 + lc];
        __syncthreads();
#pragma unroll
        for (int kk = 0; kk < 8; ++kk) {
            const float4 av = *(const float4*)&As[kk][ty * 4];
            const float4 bv = *(const float4*)&Bs[kk][tx * 4];
            const float a_[4] = {av.x, av.y, av.z, av.w};
            const float b_[4] = {bv.x, bv.y, bv.z, bv.w};
#pragma unroll
            for (int r = 0; r < 4; ++r)
#pragma unroll
                for (int c = 0; c < 4; ++c)
                    acc[r][c] = fmaf(a_[r], b_[c], acc[r][c]);
        }
        __syncthreads();
    }
    const int row = row0 + ty * 4, col = col0 + tx * 4;
#pragma unroll
    for (int r = 0; r < 4; ++r) {
        float4 o;
        o.x = expf(acc[r][0] * 0.0625f);
        o.y = expf(acc[r][1] * 0.0625f);
        o.z = expf(acc[r][2] * 0.0625f);
        o.w = expf(acc[r][3] * 0.0625f);
        *(float4*)(E + (size_t)(row + r) * SP + col) = o;
    }
}

// ---------------- K2a: bins, wv init, barrier init ----------------
__global__ __launch_bounds__(256) void k_init(float* __restrict__ E,
                                              float* __restrict__ wv,
                                              unsigned* __restrict__ bar,
                                              const float* __restrict__ alpha) {
    const int t = blockIdx.x * 256 + threadIdx.x;
    const float ea = expf(alpha[0]);
    if (t < NINNER) E[(size_t)t * SP + NINNER] = ea;        // bin column
    if (t <= NINNER) E[(size_t)NINNER * SP + t] = ea;       // bin row (+corner)
    if (t < 2176) wv[t] = (t <= NINNER) ? 1.0f : 0.0f;      // v0 = 0 -> wv = 1
    if (t < 4096) bar[t] = 0u;
}

// ---------------- K2b: F = E^T ----------------
__global__ __launch_bounds__(256) void k_transpose(const float* __restrict__ E,
                                                   float* __restrict__ F) {
    __shared__ float tle[32][33];
    const int tx = threadIdx.x & 31;
    const int ty4 = (threadIdx.x >> 5) * 4;
    const int bx = blockIdx.x * 32, by = blockIdx.y * 32;
#pragma unroll
    for (int k = 0; k < 4; ++k) {
        const int i = by + ty4 + k, j = bx + tx;
        if (i < NROW && j < NROW) tle[ty4 + k][tx] = E[(size_t)i * SP + j];
    }
    __syncthreads();
#pragma unroll
    for (int k = 0; k < 4; ++k) {
        const int j = bx + ty4 + k, i = by + tx;
        if (i < NROW && j < NROW) F[(size_t)j * SP + i] = tle[tx][ty4 + k];
    }
}

// ---------------- grid barrier v3: flat per-block epoch flags ----------------
// Arrival: leader stores monotone epoch to its own flag (no RMW, no reset).
// __syncthreads() before it guarantees every wave drained vmcnt -> all
// publish stores are at the coherence point before the flag goes out.
// Observe: thread t polls flags[t] (all 256 blocks covered in parallel,
// coalesced 64-dword wave reads). One fabric hop on the critical path.
__device__ __forceinline__ void grid_barrier(unsigned* flags, unsigned& epoch) {
    __syncthreads();
    ++epoch;
    if (threadIdx.x == 0)
        __hip_atomic_store(flags + blockIdx.x, epoch, __ATOMIC_RELAXED, __HIP_MEMORY_SCOPE_AGENT);
    while (__hip_atomic_load(flags + threadIdx.x, __ATOMIC_RELAXED, __HIP_MEMORY_SCOPE_AGENT) < epoch)
        __builtin_amdgcn_s_sleep(1);
    __builtin_amdgcn_fence(__ATOMIC_ACQUIRE, "agent");
    __syncthreads();
}

// ---------------- K3: persistent Sinkhorn ----------------
// Block b owns rows [8b,8b+8) of E and cols [8b,8b+8) of F in registers.
// j-mapping per thread: lo: j=4*tid+k, hi: j=1024+4*tid+k  -> wu/wv read as
// coalesced float4 NORMAL loads (fresh: barrier acquire fence invalidates
// L1/L2; writes are cache-bypassing relaxed atomics).
__global__ __launch_bounds__(256, 1) void k_sinkhorn(const float* __restrict__ E,
                                                     const float* __restrict__ F,
                                                     float* wu, float* wv,
                                                     unsigned* bar,
                                                     const float* __restrict__ alpha) {
    const int b = blockIdx.x, tid = threadIdx.x;
    const int lane = tid & 63, wid = tid >> 6;
    const int base = b * 8;
    const bool last = (b == NB - 1);
    __shared__ float red[4][9];

    const float norm = -8.317766166719343f;            // -log(4096)
    const float logbin = 7.624618986159398f + norm;     // log(2048) + norm
    const float ea = expf(alpha[0]);

    // register-resident fragments, j-mapped to the float4 exchange layout
    float4 elo[8], ehi[8], flo[8], fhi[8];
#pragma unroll
    for (int r = 0; r < 8; ++r) {
        const float* rowE = E + (size_t)(base + r) * SP;
        const float* rowF = F + (size_t)(base + r) * SP;
        elo[r] = *(const float4*)(rowE + 4 * tid);
        ehi[r] = *(const float4*)(rowE + 1024 + 4 * tid);
        flo[r] = *(const float4*)(rowF + 4 * tid);
        fhi[r] = *(const float4*)(rowF + 1024 + 4 * tid);
    }

    const float4* wv4 = (const float4*)wv;
    const float4* wu4 = (const float4*)wu;

    float u = 0.0f, v = 0.0f;      // potentials for row/col base+tid (tid<8)
    float ub = 0.0f, vb = 0.0f;    // dustbin potentials (block 255, tid 8)
    unsigned epoch = 0;

    for (int it = 0; it < ITERS_N; ++it) {
        // ---- phase A: S_i = sum_j E_ij wv_j -> update u, publish wu ----
        {
            const float4 wa = wv4[tid];
            const float4 wh = wv4[256 + tid];
            const float  wd = (tid == 0) ? wv[2048] : 0.0f;
            float p[8];
#pragma unroll
            for (int r = 0; r < 8; ++r) {
                p[r] = elo[r].x * wa.x + elo[r].y * wa.y + elo[r].z * wa.z + elo[r].w * wa.w
                     + ehi[r].x * wh.x + ehi[r].y * wh.y + ehi[r].z * wh.z + ehi[r].w * wh.w
                     + ea * wd;
            }
            float t = wa.x + wa.y + wa.z + wa.w + wh.x + wh.y + wh.z + wh.w + wd;
#pragma unroll
            for (int r = 0; r < 8; ++r) {
                float s = p[r];
#pragma unroll
                for (int m = 1; m < 64; m <<= 1) s += __shfl_xor(s, m, 64);
                if (lane == 0) red[wid][r] = s;
            }
#pragma unroll
            for (int m = 1; m < 64; m <<= 1) t += __shfl_xor(t, m, 64);
            if (lane == 0) red[wid][8] = t;
            __syncthreads();
            if (tid < 8) {
                const float S = red[0][tid] + red[1][tid] + red[2][tid] + red[3][tid];
                const float unew = (norm - logf(S)) / TAU_F;
                u = u + EPS_F * (unew - u);
                __hip_atomic_store(wu + base + tid, expf(u), __ATOMIC_RELAXED, __HIP_MEMORY_SCOPE_AGENT);
            }
            if (last && tid == 8) {
                const float S = ea * (red[0][8] + red[1][8] + red[2][8] + red[3][8]);
                const float unew = (logbin - logf(S)) / TAU_F;
                ub = ub + EPS_F * (unew - ub);
                __hip_atomic_store(wu + NINNER, expf(ub), __ATOMIC_RELAXED, __HIP_MEMORY_SCOPE_AGENT);
            }
        }
        grid_barrier(bar, epoch);
        // ---- phase B: T_j = sum_i F_ji wu_i -> update v, publish wv ----
        {
            const float4 wa = wu4[tid];
            const float4 wh = wu4[256 + tid];
            const float  wd = (tid == 0) ? wu[2048] : 0.0f;
            float p[8];
#pragma unroll
            for (int r = 0; r < 8; ++r) {
                p[r] = flo[r].x * wa.x + flo[r].y * wa.y + flo[r].z * wa.z + flo[r].w * wa.w
                     + fhi[r].x * wh.x + fhi[r].y * wh.y + fhi[r].z * wh.z + fhi[r].w * wh.w
                     + ea * wd;
            }
            float t = wa.x + wa.y + wa.z + wa.w + wh.x + wh.y + wh.z + wh.w + wd;
#pragma unroll
            for (int r = 0; r < 8; ++r) {
                float s = p[r];
#pragma unroll
                for (int m = 1; m < 64; m <<= 1) s += __shfl_xor(s, m, 64);
                if (lane == 0) red[wid][r] = s;
            }
#pragma unroll
            for (int m = 1; m < 64; m <<= 1) t += __shfl_xor(t, m, 64);
            if (lane == 0) red[wid][8] = t;
            __syncthreads();
            if (tid < 8) {
                const float T = red[0][tid] + red[1][tid] + red[2][tid] + red[3][tid];
                const float vnew = (norm - logf(T)) / TAU_F;
                v = v + EPS_F * (vnew - v);
                __hip_atomic_store(wv + base + tid, expf(v), __ATOMIC_RELAXED, __HIP_MEMORY_SCOPE_AGENT);
            }
            if (last && tid == 8) {
                const float T = ea * (red[0][8] + red[1][8] + red[2][8] + red[3][8]);
                const float vnew = (logbin - logf(T)) / TAU_F;
                vb = vb + EPS_F * (vnew - vb);
                __hip_atomic_store(wv + NINNER, expf(vb), __ATOMIC_RELAXED, __HIP_MEMORY_SCOPE_AGENT);
            }
        }
        // last barrier elided: kernel end is the sync point for the epilogue
        if (it != ITERS_N - 1) grid_barrier(bar, epoch);
    }
}

// ---------------- K4: out0 = exp(Z) + row max/argmax ----------------
__global__ __launch_bounds__(256) void k_rowpass(const float* __restrict__ E,
                                                 const float* __restrict__ wu,
                                                 const float* __restrict__ wv,
                                                 float* __restrict__ out,
                                                 float* __restrict__ max0,
                                                 int* __restrict__ idx0) {
    const int i = blockIdx.x;                 // 0..2048
    const int tid = threadIdx.x;
    const int lane = tid & 63, wid = tid >> 6;
    const float wui = wu[i] * 4096.0f;        // * exp(-norm)
    const float* row = E + (size_t)i * SP;
    float best = -1.0f; int bidx = 0;
    for (int j = tid; j < NROW; j += 256) {
        const float val = row[j] * wv[j] * wui;
        out[(size_t)i * NROW + j] = val;
        if (j < NINNER && val > best) { best = val; bidx = j; }
    }
    if (i < NINNER) {
        __shared__ float sb[4]; __shared__ int si[4];
#pragma unroll
        for (int m = 1; m < 64; m <<= 1) {
            const float ob = __shfl_xor(best, m, 64);
            const int   oi = __shfl_xor(bidx, m, 64);
            if (ob > best || (ob == best && oi < bidx)) { best = ob; bidx = oi; }
        }
        if (lane == 0) { sb[wid] = best; si[wid] = bidx; }
        __syncthreads();
        if (tid == 0) {
            for (int k = 1; k < 4; ++k)
                if (sb[k] > best || (sb[k] == best && si[k] < bidx)) { best = sb[k]; bidx = si[k]; }
            max0[i] = best; idx0[i] = bidx;
        }
    }
}

// ---------------- K5: col argmax via F ----------------
__global__ __launch_bounds__(256) void k_colpass(const float* __restrict__ F,
                                                 const float* __restrict__ wu,
                                                 int* __restrict__ idx1) {
    const int j = blockIdx.x;                 // 0..2047
    const int tid = threadIdx.x;
    const int lane = tid & 63, wid = tid >> 6;
    const float* row = F + (size_t)j * SP;
    float best = -1.0f; int bidx = 0;
    for (int i = tid; i < NINNER; i += 256) {
        const float q = row[i] * wu[i];
        if (q > best) { best = q; bidx = i; }
    }
    __shared__ float sb[4]; __shared__ int si[4];
#pragma unroll
    for (int m = 1; m < 64; m <<= 1) {
        const float ob = __shfl_xor(best, m, 64);
        const int   oi = __shfl_xor(bidx, m, 64);
        if (ob > best || (ob == best && oi < bidx)) { best = ob; bidx = oi; }
    }
    if (lane == 0) { sb[wid] = best; si[wid] = bidx; }
    __syncthreads();
    if (tid == 0) {
        for (int k = 1; k < 4; ++k)
            if (sb[k] > best || (sb[k] == best && si[k] < bidx)) { best = sb[k]; bidx = si[k]; }
        idx1[j] = bidx;
    }
}

// ---------------- K6a/K6b: mutual matching ----------------
__global__ __launch_bounds__(256) void k_match0(const float* __restrict__ max0,
                                                const int* __restrict__ idx0,
                                                const int* __restrict__ idx1,
                                                float* __restrict__ ms0,
                                                int* __restrict__ vld0,
                                                float* __restrict__ out) {
    const int i = blockIdx.x * 256 + threadIdx.x;
    if (i >= NINNER) return;
    const int j = idx0[i];
    const bool mut = (idx1[j] == i);
    const float ms = mut ? max0[i] : 0.0f;
    const bool val = mut && (ms > 0.2f);
    ms0[i] = ms; vld0[i] = val ? 1 : 0;
    out[OOFF_I0 + i] = val ? (float)j : -1.0f;
    out[OOFF_S0 + i] = ms;
}
__global__ __launch_bounds__(256) void k_match1(const int* __restrict__ idx0,
                                                const int* __restrict__ idx1,
                                                const float* __restrict__ ms0,
                                                const int* __restrict__ vld0,
                                                float* __restrict__ out) {
    const int j = blockIdx.x * 256 + threadIdx.x;
    if (j >= NINNER) return;
    const int i = idx1[j];
    const bool mut = (idx0[i] == j);
    const float ms = mut ? ms0[i] : 0.0f;
    const bool val = mut && (vld0[i] != 0);
    out[OOFF_I1 + j] = val ? (float)i : -1.0f;
    out[OOFF_S1 + j] = ms;
}

// ---------------- host ----------------
extern "C" void kernel_launch(void* const* d_in, const int* in_sizes, int n_in,
                              void* d_out, int out_size, void* d_ws, size_t ws_size,
                              hipStream_t stream) {
    const float* A     = (const float*)d_in[0];   // mdesc0 (1,256,2048)
    const float* Bm    = (const float*)d_in[1];   // mdesc1 (1,256,2048)
    const float* alpha = (const float*)d_in[2];   // bin_score scalar

    float* ws = (float*)d_ws;
    float*    E    = ws + OFF_E;
    float*    F    = ws + OFF_F;
    float*    wu   = ws + OFF_WU;
    float*    wv   = ws + OFF_WV;
    unsigned* bar  = (unsigned*)(ws + OFF_BAR);
    float*    max0 = ws + OFF_MAX0;
    int*      idx0 = (int*)(ws + OFF_IDX0);
    int*      idx1 = (int*)(ws + OFF_IDX1);
    float*    ms0  = ws + OFF_MS0;
    int*      vld0 = (int*)(ws + OFF_VLD0);
    float*    out  = (float*)d_out;

    k_gemm<<<dim3(32, 32), 256, 0, stream>>>(A, Bm, E);
    k_init<<<dim3(16), 256, 0, stream>>>(E, wv, bar, alpha);
    k_transpose<<<dim3(65, 65), 256, 0, stream>>>(E, F);
    k_sinkhorn<<<dim3(NB), NT, 0, stream>>>(E, F, wu, wv, bar, alpha);
    k_rowpass<<<dim3(NROW), 256, 0, stream>>>(E, wu, wv, out, max0, idx0);
    k_colpass<<<dim3(NINNER), 256, 0, stream>>>(F, wu, idx1);
    k_match0<<<dim3(8), 256, 0, stream>>>(max0, idx0, idx1, ms0, vld0, out);
    k_match1<<<dim3(8), 256, 0, stream>>>(idx0, idx1, ms0, vld0, out);
}

// Round 5
// 952.878 us; speedup vs baseline: 2.6554x; 2.6554x over previous
//
#include <hip/hip_runtime.h>
#include <hip/hip_bf16.h>
#include <math.h>

// ---------------- problem constants ----------------
#define D        256
#define NINNER   2048
#define NROW     2049          // 2048 + dustbin
#define SP       2064          // padded row stride (floats), 16B-aligned rows
#define ITERS_N  100
#define EPS_F    0.8f
#define TAU_F    1.02f
#define NB       256           // persistent blocks
#define NT       256           // threads per block

typedef unsigned long long u64;

// pair buffers: u64 slots, (tag<<32)|float_bits, double-buffered by tag parity
#define PSTRIDE  2112u         // pairs per buffer (2049 used, padded)

// ws layout (in floats)
#define SZ_MAT   (2049u * 2064u)          // 4229136
#define OFF_E    0u
#define OFF_F    SZ_MAT
#define OFF_WUP  (2u * SZ_MAT)                  // u64[2][PSTRIDE] = 4*PSTRIDE floats
#define OFF_WVP  (OFF_WUP + 4u * PSTRIDE)
#define OFF_MAX0 (OFF_WVP + 4u * PSTRIDE)
#define OFF_IDX0 (OFF_MAX0 + 2048u)
#define OFF_IDX1 (OFF_IDX0 + 2048u)
#define OFF_MS0  (OFF_IDX1 + 2048u)
#define OFF_VLD0 (OFF_MS0 + 2048u)

// d_out layout (floats)
#define OOFF_Z   0u
#define OOFF_I0  (2049u * 2049u)          // 4198401
#define OOFF_I1  (OOFF_I0 + 2048u)
#define OOFF_S0  (OOFF_I1 + 2048u)
#define OOFF_S1  (OOFF_S0 + 2048u)

__device__ __forceinline__ float    pair_val(u64 x) { return __uint_as_float((unsigned)x); }
__device__ __forceinline__ unsigned pair_tag(u64 x) { return (unsigned)(x >> 32); }
__device__ __forceinline__ u64 make_pair(float v, unsigned t) {
    return ((u64)t << 32) | (u64)__float_as_uint(v);
}

// ---------------- K1: fp32 GEMM -> E = exp(scores) ----------------
__global__ __launch_bounds__(256) void k_gemm(const float* __restrict__ A,
                                              const float* __restrict__ Bm,
                                              float* __restrict__ E) {
    __shared__ float As[8][64];
    __shared__ float Bs[8][64];
    const int tid = threadIdx.x;
    const int tx = tid & 15, ty = tid >> 4;
    const int row0 = blockIdx.y * 64, col0 = blockIdx.x * 64;
    float acc[4][4] = {};
    const int lr = tid >> 6, lc = tid & 63;
    for (int k0 = 0; k0 < D; k0 += 8) {
        As[lr][lc]     = A[(k0 + lr) * NINNER + row0 + lc];
        As[lr + 4][lc] = A[(k0 + lr + 4) * NINNER + row0 + lc];
        Bs[lr][lc]     = Bm[(k0 + lr) * NINNER + col0 + lc];
        Bs[lr + 4][lc] = Bm[(k0 + lr + 4) * NINNER + col0 + lc];
        __syncthreads();
#pragma unroll
        for (int kk = 0; kk < 8; ++kk) {
            const float4 av = *(const float4*)&As[kk][ty * 4];
            const float4 bv = *(const float4*)&Bs[kk][tx * 4];
            const float a_[4] = {av.x, av.y, av.z, av.w};
            const float b_[4] = {bv.x, bv.y, bv.z, bv.w};
#pragma unroll
            for (int r = 0; r < 4; ++r)
#pragma unroll
                for (int c = 0; c < 4; ++c)
                    acc[r][c] = fmaf(a_[r], b_[c], acc[r][c]);
        }
        __syncthreads();
    }
    const int row = row0 + ty * 4, col = col0 + tx * 4;
#pragma unroll
    for (int r = 0; r < 4; ++r) {
        float4 o;
        o.x = expf(acc[r][0] * 0.0625f);
        o.y = expf(acc[r][1] * 0.0625f);
        o.z = expf(acc[r][2] * 0.0625f);
        o.w = expf(acc[r][3] * 0.0625f);
        *(float4*)(E + (size_t)(row + r) * SP + col) = o;
    }
}

// ---------------- K2a: bins + wv pair init (tag 0) ----------------
__global__ __launch_bounds__(256) void k_init(float* __restrict__ E,
                                              u64* __restrict__ wvb0,
                                              const float* __restrict__ alpha) {
    const int t = blockIdx.x * 256 + threadIdx.x;
    const float ea = expf(alpha[0]);
    if (t < NINNER) E[(size_t)t * SP + NINNER] = ea;        // bin column
    if (t <= NINNER) E[(size_t)NINNER * SP + t] = ea;       // bin row (+corner)
    if (t <= NINNER) wvb0[t] = make_pair(1.0f, 0u);         // v0 = 0 -> wv = 1, tag 0
}

// ---------------- K2b: F = E^T ----------------
__global__ __launch_bounds__(256) void k_transpose(const float* __restrict__ E,
                                                   float* __restrict__ F) {
    __shared__ float tle[32][33];
    const int tx = threadIdx.x & 31;
    const int ty4 = (threadIdx.x >> 5) * 4;
    const int bx = blockIdx.x * 32, by = blockIdx.y * 32;
#pragma unroll
    for (int k = 0; k < 4; ++k) {
        const int i = by + ty4 + k, j = bx + tx;
        if (i < NROW && j < NROW) tle[ty4 + k][tx] = E[(size_t)i * SP + j];
    }
    __syncthreads();
#pragma unroll
    for (int k = 0; k < 4; ++k) {
        const int j = bx + ty4 + k, i = by + tx;
        if (i < NROW && j < NROW) F[(size_t)j * SP + i] = tle[tx][ty4 + k];
    }
}

// poll 8 tagged pairs: slot q*256+tid (coalesced 512B/wave), tag must EQUAL want
__device__ __forceinline__ void poll8(u64* buf, int tid, unsigned want, float* w) {
    for (;;) {
        u64 a0 = __hip_atomic_load(buf + 0 * 256 + tid, __ATOMIC_RELAXED, __HIP_MEMORY_SCOPE_AGENT);
        u64 a1 = __hip_atomic_load(buf + 1 * 256 + tid, __ATOMIC_RELAXED, __HIP_MEMORY_SCOPE_AGENT);
        u64 a2 = __hip_atomic_load(buf + 2 * 256 + tid, __ATOMIC_RELAXED, __HIP_MEMORY_SCOPE_AGENT);
        u64 a3 = __hip_atomic_load(buf + 3 * 256 + tid, __ATOMIC_RELAXED, __HIP_MEMORY_SCOPE_AGENT);
        u64 a4 = __hip_atomic_load(buf + 4 * 256 + tid, __ATOMIC_RELAXED, __HIP_MEMORY_SCOPE_AGENT);
        u64 a5 = __hip_atomic_load(buf + 5 * 256 + tid, __ATOMIC_RELAXED, __HIP_MEMORY_SCOPE_AGENT);
        u64 a6 = __hip_atomic_load(buf + 6 * 256 + tid, __ATOMIC_RELAXED, __HIP_MEMORY_SCOPE_AGENT);
        u64 a7 = __hip_atomic_load(buf + 7 * 256 + tid, __ATOMIC_RELAXED, __HIP_MEMORY_SCOPE_AGENT);
        const bool ok = (pair_tag(a0) == want) & (pair_tag(a1) == want)
                      & (pair_tag(a2) == want) & (pair_tag(a3) == want)
                      & (pair_tag(a4) == want) & (pair_tag(a5) == want)
                      & (pair_tag(a6) == want) & (pair_tag(a7) == want);
        if (ok) {
            w[0] = pair_val(a0); w[1] = pair_val(a1); w[2] = pair_val(a2); w[3] = pair_val(a3);
            w[4] = pair_val(a4); w[5] = pair_val(a5); w[6] = pair_val(a6); w[7] = pair_val(a7);
            return;
        }
        __builtin_amdgcn_s_sleep(1);
    }
}

__device__ __forceinline__ float poll_bin(u64* buf, unsigned want) {
    for (;;) {
        u64 d = __hip_atomic_load(buf + NINNER, __ATOMIC_RELAXED, __HIP_MEMORY_SCOPE_AGENT);
        if (pair_tag(d) == want) return pair_val(d);
        __builtin_amdgcn_s_sleep(1);
    }
}

// ---------------- K3: persistent Sinkhorn — BARRIER-FREE dataflow ----------------
// Block b owns rows [8b,8b+8) of E and cols [8b,8b+8) of F in registers
// (eR/fR[r][q] = matrix[base+r][q*256+tid], constant indexing -> VGPRs).
// wu/wv exchanged as (tag,value) 8B atoms, double-buffered by tag parity:
//   wv tag e lives in wvb[e&1]; phase A of iter t consumes wv tag t,
//   produces wu tag t+1 -> wub[(t+1)&1]; phase B consumes wu tag t+1,
//   produces wv tag t+1. Skew bound < 2 iters per parity buffer => tag==want
//   is always eventually satisfied (no deadlock), and 0xAA poison never
//   matches a wanted tag (0..100).
__global__ __launch_bounds__(256, 1) void k_sinkhorn(const float* __restrict__ E,
                                                     const float* __restrict__ F,
                                                     u64* wub, u64* wvb,
                                                     const float* __restrict__ alpha) {
    const int b = blockIdx.x, tid = threadIdx.x;
    const int lane = tid & 63, wid = tid >> 6;
    const int base = b * 8;
    const bool lastb = (b == NB - 1);
    __shared__ float red[2][4][9];

    const float norm = -8.317766166719343f;            // -log(4096)
    const float logbin = 7.624618986159398f + norm;     // log(2048) + norm
    const float ea = expf(alpha[0]);

    float eR[8][8], fR[8][8];
#pragma unroll
    for (int r = 0; r < 8; ++r) {
        const float* rowE = E + (size_t)(base + r) * SP;
        const float* rowF = F + (size_t)(base + r) * SP;
#pragma unroll
        for (int q = 0; q < 8; ++q) {
            eR[r][q] = rowE[q * 256 + tid];
            fR[r][q] = rowF[q * 256 + tid];
        }
    }

    float u = 0.0f, v = 0.0f;      // potentials for row/col base+tid (tid<8)
    float ub = 0.0f, vb = 0.0f;    // dustbin potentials (block 255, tid 8)

    for (int it = 0; it < ITERS_N; ++it) {
        // ---- phase A: consume wv tag it, produce wu tag it+1 ----
        {
            u64* src = wvb + (size_t)(it & 1) * PSTRIDE;
            u64* dst = wub + (size_t)((it + 1) & 1) * PSTRIDE;
            const unsigned want = (unsigned)it, prod = (unsigned)(it + 1);
            float w[8];
            poll8(src, tid, want, w);
            const float wd = (tid == 0) ? poll_bin(src, want) : 0.0f;
            float p[8];
#pragma unroll
            for (int r = 0; r < 8; ++r) {
                float s = ea * wd;
#pragma unroll
                for (int q = 0; q < 8; ++q) s = fmaf(eR[r][q], w[q], s);
                p[r] = s;
            }
            float t = w[0] + w[1] + w[2] + w[3] + w[4] + w[5] + w[6] + w[7] + wd;
#pragma unroll
            for (int r = 0; r < 8; ++r) {
                float s = p[r];
#pragma unroll
                for (int m = 1; m < 64; m <<= 1) s += __shfl_xor(s, m, 64);
                if (lane == 0) red[0][wid][r] = s;
            }
#pragma unroll
            for (int m = 1; m < 64; m <<= 1) t += __shfl_xor(t, m, 64);
            if (lane == 0) red[0][wid][8] = t;
            __syncthreads();
            if (tid < 8) {
                const float S = red[0][0][tid] + red[0][1][tid] + red[0][2][tid] + red[0][3][tid];
                const float unew = (norm - logf(S)) / TAU_F;
                u = u + EPS_F * (unew - u);
                __hip_atomic_store(dst + base + tid, make_pair(expf(u), prod),
                                   __ATOMIC_RELAXED, __HIP_MEMORY_SCOPE_AGENT);
            }
            if (lastb && tid == 8) {
                const float S = ea * (red[0][0][8] + red[0][1][8] + red[0][2][8] + red[0][3][8]);
                const float unew = (logbin - logf(S)) / TAU_F;
                ub = ub + EPS_F * (unew - ub);
                __hip_atomic_store(dst + NINNER, make_pair(expf(ub), prod),
                                   __ATOMIC_RELAXED, __HIP_MEMORY_SCOPE_AGENT);
            }
        }
        // ---- phase B: consume wu tag it+1, produce wv tag it+1 ----
        {
            u64* src = wub + (size_t)((it + 1) & 1) * PSTRIDE;
            u64* dst = wvb + (size_t)((it + 1) & 1) * PSTRIDE;
            const unsigned want = (unsigned)(it + 1), prod = (unsigned)(it + 1);
            float w[8];
            poll8(src, tid, want, w);
            const float wd = (tid == 0) ? poll_bin(src, want) : 0.0f;
            float p[8];
#pragma unroll
            for (int r = 0; r < 8; ++r) {
                float s = ea * wd;
#pragma unroll
                for (int q = 0; q < 8; ++q) s = fmaf(fR[r][q], w[q], s);
                p[r] = s;
            }
            float t = w[0] + w[1] + w[2] + w[3] + w[4] + w[5] + w[6] + w[7] + wd;
#pragma unroll
            for (int r = 0; r < 8; ++r) {
                float s = p[r];
#pragma unroll
                for (int m = 1; m < 64; m <<= 1) s += __shfl_xor(s, m, 64);
                if (lane == 0) red[1][wid][r] = s;
            }
#pragma unroll
            for (int m = 1; m < 64; m <<= 1) t += __shfl_xor(t, m, 64);
            if (lane == 0) red[1][wid][8] = t;
            __syncthreads();
            if (tid < 8) {
                const float T = red[1][0][tid] + red[1][1][tid] + red[1][2][tid] + red[1][3][tid];
                const float vnew = (norm - logf(T)) / TAU_F;
                v = v + EPS_F * (vnew - v);
                __hip_atomic_store(dst + base + tid, make_pair(expf(v), prod),
                                   __ATOMIC_RELAXED, __HIP_MEMORY_SCOPE_AGENT);
            }
            if (lastb && tid == 8) {
                const float T = ea * (red[1][0][8] + red[1][1][8] + red[1][2][8] + red[1][3][8]);
                const float vnew = (logbin - logf(T)) / TAU_F;
                vb = vb + EPS_F * (vnew - vb);
                __hip_atomic_store(dst + NINNER, make_pair(expf(vb), prod),
                                   __ATOMIC_RELAXED, __HIP_MEMORY_SCOPE_AGENT);
            }
        }
    }
}

// ---------------- K4: out0 = exp(Z) + row max/argmax ----------------
// final wu/wv: tag 100 -> parity buffer 0 -> read .x of float2 pairs
__global__ __launch_bounds__(256) void k_rowpass(const float* __restrict__ E,
                                                 const float2* __restrict__ wup,
                                                 const float2* __restrict__ wvp,
                                                 float* __restrict__ out,
                                                 float* __restrict__ max0,
                                                 int* __restrict__ idx0) {
    const int i = blockIdx.x;                 // 0..2048
    const int tid = threadIdx.x;
    const int lane = tid & 63, wid = tid >> 6;
    const float wui = wup[i].x * 4096.0f;     // * exp(-norm)
    const float* row = E + (size_t)i * SP;
    float best = -1.0f; int bidx = 0;
    for (int j = tid; j < NROW; j += 256) {
        const float val = row[j] * wvp[j].x * wui;
        out[(size_t)i * NROW + j] = val;
        if (j < NINNER && val > best) { best = val; bidx = j; }
    }
    if (i < NINNER) {
        __shared__ float sb[4]; __shared__ int si[4];
#pragma unroll
        for (int m = 1; m < 64; m <<= 1) {
            const float ob = __shfl_xor(best, m, 64);
            const int   oi = __shfl_xor(bidx, m, 64);
            if (ob > best || (ob == best && oi < bidx)) { best = ob; bidx = oi; }
        }
        if (lane == 0) { sb[wid] = best; si[wid] = bidx; }
        __syncthreads();
        if (tid == 0) {
            for (int k = 1; k < 4; ++k)
                if (sb[k] > best || (sb[k] == best && si[k] < bidx)) { best = sb[k]; bidx = si[k]; }
            max0[i] = best; idx0[i] = bidx;
        }
    }
}

// ---------------- K5: col argmax via F ----------------
__global__ __launch_bounds__(256) void k_colpass(const float* __restrict__ F,
                                                 const float2* __restrict__ wup,
                                                 int* __restrict__ idx1) {
    const int j = blockIdx.x;                 // 0..2047
    const int tid = threadIdx.x;
    const int lane = tid & 63, wid = tid >> 6;
    const float* row = F + (size_t)j * SP;
    float best = -1.0f; int bidx = 0;
    for (int i = tid; i < NINNER; i += 256) {
        const float q = row[i] * wup[i].x;
        if (q > best) { best = q; bidx = i; }
    }
    __shared__ float sb[4]; __shared__ int si[4];
#pragma unroll
    for (int m = 1; m < 64; m <<= 1) {
        const float ob = __shfl_xor(best, m, 64);
        const int   oi = __shfl_xor(bidx, m, 64);
        if (ob > best || (ob == best && oi < bidx)) { best = ob; bidx = oi; }
    }
    if (lane == 0) { sb[wid] = best; si[wid] = bidx; }
    __syncthreads();
    if (tid == 0) {
        for (int k = 1; k < 4; ++k)
            if (sb[k] > best || (sb[k] == best && si[k] < bidx)) { best = sb[k]; bidx = si[k]; }
        idx1[j] = bidx;
    }
}

// ---------------- K6a/K6b: mutual matching ----------------
__global__ __launch_bounds__(256) void k_match0(const float* __restrict__ max0,
                                                const int* __restrict__ idx0,
                                                const int* __restrict__ idx1,
                                                float* __restrict__ ms0,
                                                int* __restrict__ vld0,
                                                float* __restrict__ out) {
    const int i = blockIdx.x * 256 + threadIdx.x;
    if (i >= NINNER) return;
    const int j = idx0[i];
    const bool mut = (idx1[j] == i);
    const float ms = mut ? max0[i] : 0.0f;
    const bool val = mut && (ms > 0.2f);
    ms0[i] = ms; vld0[i] = val ? 1 : 0;
    out[OOFF_I0 + i] = val ? (float)j : -1.0f;
    out[OOFF_S0 + i] = ms;
}
__global__ __launch_bounds__(256) void k_match1(const int* __restrict__ idx0,
                                                const int* __restrict__ idx1,
                                                const float* __restrict__ ms0,
                                                const int* __restrict__ vld0,
                                                float* __restrict__ out) {
    const int j = blockIdx.x * 256 + threadIdx.x;
    if (j >= NINNER) return;
    const int i = idx1[j];
    const bool mut = (idx0[i] == j);
    const float ms = mut ? ms0[i] : 0.0f;
    const bool val = mut && (vld0[i] != 0);
    out[OOFF_I1 + j] = val ? (float)i : -1.0f;
    out[OOFF_S1 + j] = ms;
}

// ---------------- host ----------------
extern "C" void kernel_launch(void* const* d_in, const int* in_sizes, int n_in,
                              void* d_out, int out_size, void* d_ws, size_t ws_size,
                              hipStream_t stream) {
    const float* A     = (const float*)d_in[0];   // mdesc0 (1,256,2048)
    const float* Bm    = (const float*)d_in[1];   // mdesc1 (1,256,2048)
    const float* alpha = (const float*)d_in[2];   // bin_score scalar

    float* ws = (float*)d_ws;
    float* E    = ws + OFF_E;
    float* F    = ws + OFF_F;
    u64*   wub  = (u64*)(ws + OFF_WUP);
    u64*   wvb  = (u64*)(ws + OFF_WVP);
    float* max0 = ws + OFF_MAX0;
    int*   idx0 = (int*)(ws + OFF_IDX0);
    int*   idx1 = (int*)(ws + OFF_IDX1);
    float* ms0  = ws + OFF_MS0;
    int*   vld0 = (int*)(ws + OFF_VLD0);
    float* out  = (float*)d_out;

    k_gemm<<<dim3(32, 32), 256, 0, stream>>>(A, Bm, E);
    k_init<<<dim3(16), 256, 0, stream>>>(E, wvb, alpha);
    k_transpose<<<dim3(65, 65), 256, 0, stream>>>(E, F);
    k_sinkhorn<<<dim3(NB), NT, 0, stream>>>(E, F, wub, wvb, alpha);
    // final tags = 100 (even) -> parity-0 halves of both pair buffers
    k_rowpass<<<dim3(NROW), 256, 0, stream>>>(E, (const float2*)wub, (const float2*)wvb,
                                              out, max0, idx0);
    k_colpass<<<dim3(NINNER), 256, 0, stream>>>(F, (const float2*)wub, idx1);
    k_match0<<<dim3(8), 256, 0, stream>>>(max0, idx0, idx1, ms0, vld0, out);
    k_match1<<<dim3(8), 256, 0, stream>>>(idx0, idx1, ms0, vld0, out);
}

// Round 6
// 918.675 us; speedup vs baseline: 2.7542x; 1.0372x over previous
//
#include <hip/hip_runtime.h>
#include <hip/hip_bf16.h>
#include <math.h>

// ---------------- problem constants ----------------
#define D        256
#define NINNER   2048
#define NROW     2049          // 2048 + dustbin
#define SP       2064          // padded row stride (floats), 16B-aligned rows
#define ITERS_N  100
#define EPS_F    0.8f
#define TAU_F    1.02f
#define NB       256           // persistent blocks
#define NT       256           // threads per block

typedef unsigned long long u64;

// pair buffers: u64 slots, (tag<<32)|float_bits, double-buffered by tag parity
#define PSTRIDE  2112u         // pairs per buffer (2049 used, padded)

// ws layout (in floats)
#define SZ_MAT   (2049u * 2064u)          // 4229136
#define OFF_E    0u
#define OFF_F    SZ_MAT
#define OFF_WUP  (2u * SZ_MAT)                  // u64[2][PSTRIDE] = 4*PSTRIDE floats
#define OFF_WVP  (OFF_WUP + 4u * PSTRIDE)
#define OFF_MAX0 (OFF_WVP + 4u * PSTRIDE)
#define OFF_IDX0 (OFF_MAX0 + 2048u)
#define OFF_IDX1 (OFF_IDX0 + 2048u)
#define OFF_MS0  (OFF_IDX1 + 2048u)
#define OFF_VLD0 (OFF_MS0 + 2048u)

// d_out layout (floats)
#define OOFF_Z   0u
#define OOFF_I0  (2049u * 2049u)          // 4198401
#define OOFF_I1  (OOFF_I0 + 2048u)
#define OOFF_S0  (OOFF_I1 + 2048u)
#define OOFF_S1  (OOFF_S0 + 2048u)

__device__ __forceinline__ float    pair_val(u64 x) { return __uint_as_float((unsigned)x); }
__device__ __forceinline__ unsigned pair_tag(u64 x) { return (unsigned)(x >> 32); }
__device__ __forceinline__ u64 make_pair(float v, unsigned t) {
    return ((u64)t << 32) | (u64)__float_as_uint(v);
}

// ---------------- K1: fp32 GEMM -> E = exp(scores), F = E^T (fused) ----------------
__global__ __launch_bounds__(256) void k_gemm(const float* __restrict__ A,
                                              const float* __restrict__ Bm,
                                              float* __restrict__ E,
                                              float* __restrict__ F) {
    __shared__ float As[8][64];
    __shared__ float Bs[8][64];
    const int tid = threadIdx.x;
    const int tx = tid & 15, ty = tid >> 4;
    const int row0 = blockIdx.y * 64, col0 = blockIdx.x * 64;
    float acc[4][4] = {};
    const int lr = tid >> 6, lc = tid & 63;
    for (int k0 = 0; k0 < D; k0 += 8) {
        As[lr][lc]     = A[(k0 + lr) * NINNER + row0 + lc];
        As[lr + 4][lc] = A[(k0 + lr + 4) * NINNER + row0 + lc];
        Bs[lr][lc]     = Bm[(k0 + lr) * NINNER + col0 + lc];
        Bs[lr + 4][lc] = Bm[(k0 + lr + 4) * NINNER + col0 + lc];
        __syncthreads();
#pragma unroll
        for (int kk = 0; kk < 8; ++kk) {
            const float4 av = *(const float4*)&As[kk][ty * 4];
            const float4 bv = *(const float4*)&Bs[kk][tx * 4];
            const float a_[4] = {av.x, av.y, av.z, av.w};
            const float b_[4] = {bv.x, bv.y, bv.z, bv.w};
#pragma unroll
            for (int r = 0; r < 4; ++r)
#pragma unroll
                for (int c = 0; c < 4; ++c)
                    acc[r][c] = fmaf(a_[r], b_[c], acc[r][c]);
        }
        __syncthreads();
    }
    float o[4][4];
#pragma unroll
    for (int r = 0; r < 4; ++r)
#pragma unroll
        for (int c = 0; c < 4; ++c)
            o[r][c] = expf(acc[r][c] * 0.0625f);
    const int row = row0 + ty * 4, col = col0 + tx * 4;
#pragma unroll
    for (int r = 0; r < 4; ++r)     // E tile: rows contiguous in col
        *(float4*)(E + (size_t)(row + r) * SP + col)
            = make_float4(o[r][0], o[r][1], o[r][2], o[r][3]);
#pragma unroll
    for (int c = 0; c < 4; ++c)     // F tile (transposed): rows contiguous in row
        *(float4*)(F + (size_t)(col + c) * SP + row)
            = make_float4(o[0][c], o[1][c], o[2][c], o[3][c]);
}

// ---------------- K2: bins for E and F + wv pair init (tag 0) ----------------
__global__ __launch_bounds__(256) void k_init(float* __restrict__ E,
                                              float* __restrict__ F,
                                              u64* __restrict__ wvb0,
                                              const float* __restrict__ alpha) {
    const int t = blockIdx.x * 256 + threadIdx.x;
    const float ea = expf(alpha[0]);
    if (t < NINNER) {
        E[(size_t)t * SP + NINNER] = ea;        // E bin column
        F[(size_t)t * SP + NINNER] = ea;        // F bin column (= E bin row)
    }
    if (t <= NINNER) {
        E[(size_t)NINNER * SP + t] = ea;        // E bin row (+corner)
        F[(size_t)NINNER * SP + t] = ea;        // F bin row (+corner)
        wvb0[t] = make_pair(1.0f, 0u);          // v0 = 0 -> wv = 1, tag 0
    }
}

// ---------------- masked hot poll: reload only stale slots, no sleep ----------------
__device__ __forceinline__ void poll8(const u64* buf, int tid, unsigned want, float* w) {
    u64 a[8];
#pragma unroll
    for (int q = 0; q < 8; ++q)
        a[q] = __hip_atomic_load(buf + q * 256 + tid, __ATOMIC_RELAXED, __HIP_MEMORY_SCOPE_AGENT);
    for (;;) {
        unsigned miss = 0u;
#pragma unroll
        for (int q = 0; q < 8; ++q)
            miss |= (pair_tag(a[q]) != want) ? (1u << q) : 0u;
        if (!miss) break;
#pragma unroll
        for (int q = 0; q < 8; ++q)
            if (miss & (1u << q))
                a[q] = __hip_atomic_load(buf + q * 256 + tid, __ATOMIC_RELAXED, __HIP_MEMORY_SCOPE_AGENT);
    }
#pragma unroll
    for (int q = 0; q < 8; ++q) w[q] = pair_val(a[q]);
}

__device__ __forceinline__ float poll_bin(const u64* buf, unsigned want) {
    for (;;) {
        u64 d = __hip_atomic_load(buf + NINNER, __ATOMIC_RELAXED, __HIP_MEMORY_SCOPE_AGENT);
        if (pair_tag(d) == want) return pair_val(d);
    }
}

// ---------------- K3: persistent Sinkhorn — barrier-free tagged dataflow ----------------
// Block b owns rows [8b,8b+8) of E and cols [8b,8b+8) of F in registers
// (eR/fR[r][q] = matrix[base+r][q*256+tid]). wu/wv exchanged as (tag,value)
// 8B atoms, double-buffered by tag parity. Skew bound < 2 iters per parity
// buffer => no deadlock; 0xAA poison never matches a wanted tag (0..100).
__global__ __launch_bounds__(256, 1) void k_sinkhorn(const float* __restrict__ E,
                                                     const float* __restrict__ F,
                                                     u64* wub, u64* wvb,
                                                     const float* __restrict__ alpha) {
    const int b = blockIdx.x, tid = threadIdx.x;
    const int lane = tid & 63, wid = tid >> 6;
    const int base = b * 8;
    const bool lastb = (b == NB - 1);
    __shared__ float red[2][4][9];

    const float norm = -8.317766166719343f;            // -log(4096)
    const float logbin = 7.624618986159398f + norm;     // log(2048) + norm
    const float ea = expf(alpha[0]);

    float eR[8][8], fR[8][8];
#pragma unroll
    for (int r = 0; r < 8; ++r) {
        const float* rowE = E + (size_t)(base + r) * SP;
        const float* rowF = F + (size_t)(base + r) * SP;
#pragma unroll
        for (int q = 0; q < 8; ++q) {
            eR[r][q] = rowE[q * 256 + tid];
            fR[r][q] = rowF[q * 256 + tid];
        }
    }

    float u = 0.0f, v = 0.0f;      // potentials for row/col base+tid (tid<8)
    float ub = 0.0f, vb = 0.0f;    // dustbin potentials (block 255, tid 8)

    for (int it = 0; it < ITERS_N; ++it) {
        // ---- phase A: consume wv tag it, produce wu tag it+1 ----
        {
            u64* src = wvb + (size_t)(it & 1) * PSTRIDE;
            u64* dst = wub + (size_t)((it + 1) & 1) * PSTRIDE;
            const unsigned want = (unsigned)it, prod = (unsigned)(it + 1);
            float w[8];
            poll8(src, tid, want, w);
            const float wd = (tid == 0) ? poll_bin(src, want) : 0.0f;
            float p[8];
#pragma unroll
            for (int r = 0; r < 8; ++r) {
                float s = ea * wd;
#pragma unroll
                for (int q = 0; q < 8; ++q) s = fmaf(eR[r][q], w[q], s);
                p[r] = s;
            }
            float t = w[0] + w[1] + w[2] + w[3] + w[4] + w[5] + w[6] + w[7] + wd;
#pragma unroll
            for (int r = 0; r < 8; ++r) {
                float s = p[r];
#pragma unroll
                for (int m = 1; m < 64; m <<= 1) s += __shfl_xor(s, m, 64);
                if (lane == 0) red[0][wid][r] = s;
            }
#pragma unroll
            for (int m = 1; m < 64; m <<= 1) t += __shfl_xor(t, m, 64);
            if (lane == 0) red[0][wid][8] = t;
            __syncthreads();
            if (tid < 8) {
                const float S = red[0][0][tid] + red[0][1][tid] + red[0][2][tid] + red[0][3][tid];
                const float unew = (norm - logf(S)) / TAU_F;
                u = u + EPS_F * (unew - u);
                __hip_atomic_store(dst + base + tid, make_pair(expf(u), prod),
                                   __ATOMIC_RELAXED, __HIP_MEMORY_SCOPE_AGENT);
            }
            if (lastb && tid == 8) {
                const float S = ea * (red[0][0][8] + red[0][1][8] + red[0][2][8] + red[0][3][8]);
                const float unew = (logbin - logf(S)) / TAU_F;
                ub = ub + EPS_F * (unew - ub);
                __hip_atomic_store(dst + NINNER, make_pair(expf(ub), prod),
                                   __ATOMIC_RELAXED, __HIP_MEMORY_SCOPE_AGENT);
            }
        }
        // ---- phase B: consume wu tag it+1, produce wv tag it+1 ----
        {
            u64* src = wub + (size_t)((it + 1) & 1) * PSTRIDE;
            u64* dst = wvb + (size_t)((it + 1) & 1) * PSTRIDE;
            const unsigned want = (unsigned)(it + 1), prod = (unsigned)(it + 1);
            float w[8];
            poll8(src, tid, want, w);
            const float wd = (tid == 0) ? poll_bin(src, want) : 0.0f;
            float p[8];
#pragma unroll
            for (int r = 0; r < 8; ++r) {
                float s = ea * wd;
#pragma unroll
                for (int q = 0; q < 8; ++q) s = fmaf(fR[r][q], w[q], s);
                p[r] = s;
            }
            float t = w[0] + w[1] + w[2] + w[3] + w[4] + w[5] + w[6] + w[7] + wd;
#pragma unroll
            for (int r = 0; r < 8; ++r) {
                float s = p[r];
#pragma unroll
                for (int m = 1; m < 64; m <<= 1) s += __shfl_xor(s, m, 64);
                if (lane == 0) red[1][wid][r] = s;
            }
#pragma unroll
            for (int m = 1; m < 64; m <<= 1) t += __shfl_xor(t, m, 64);
            if (lane == 0) red[1][wid][8] = t;
            __syncthreads();
            if (tid < 8) {
                const float T = red[1][0][tid] + red[1][1][tid] + red[1][2][tid] + red[1][3][tid];
                const float vnew = (norm - logf(T)) / TAU_F;
                v = v + EPS_F * (vnew - v);
                __hip_atomic_store(dst + base + tid, make_pair(expf(v), prod),
                                   __ATOMIC_RELAXED, __HIP_MEMORY_SCOPE_AGENT);
            }
            if (lastb && tid == 8) {
                const float T = ea * (red[1][0][8] + red[1][1][8] + red[1][2][8] + red[1][3][8]);
                const float vnew = (logbin - logf(T)) / TAU_F;
                vb = vb + EPS_F * (vnew - vb);
                __hip_atomic_store(dst + NINNER, make_pair(expf(vb), prod),
                                   __ATOMIC_RELAXED, __HIP_MEMORY_SCOPE_AGENT);
            }
        }
    }
}

// ---------------- K4: fused epilogue — out0 = exp(Z), row argmax, col argmax ----------
// final wu/wv: tag 100 (even) -> parity-0 buffer halves -> .x of float2 pairs
__global__ __launch_bounds__(256) void k_finish(const float* __restrict__ E,
                                                const float* __restrict__ F,
                                                const float2* __restrict__ wup,
                                                const float2* __restrict__ wvp,
                                                float* __restrict__ out,
                                                float* __restrict__ max0,
                                                int* __restrict__ idx0,
                                                int* __restrict__ idx1) {
    const int i = blockIdx.x;                 // 0..2048
    const int tid = threadIdx.x;
    const int lane = tid & 63, wid = tid >> 6;
    __shared__ float sb[4]; __shared__ int si[4];

    // --- row part: write out row i, argmax over inner cols ---
    {
        const float wui = wup[i].x * 4096.0f;     // * exp(-norm)
        const float* row = E + (size_t)i * SP;
        float best = -1.0f; int bidx = 0;
        for (int j = tid; j < NROW; j += 256) {
            const float val = row[j] * wvp[j].x * wui;
            out[(size_t)i * NROW + j] = val;
            if (j < NINNER && val > best) { best = val; bidx = j; }
        }
        if (i < NINNER) {
#pragma unroll
            for (int m = 1; m < 64; m <<= 1) {
                const float ob = __shfl_xor(best, m, 64);
                const int   oi = __shfl_xor(bidx, m, 64);
                if (ob > best || (ob == best && oi < bidx)) { best = ob; bidx = oi; }
            }
            if (lane == 0) { sb[wid] = best; si[wid] = bidx; }
            __syncthreads();
            if (tid == 0) {
                for (int k = 1; k < 4; ++k)
                    if (sb[k] > best || (sb[k] == best && si[k] < bidx)) { best = sb[k]; bidx = si[k]; }
                max0[i] = best; idx0[i] = bidx;
            }
        }
    }

    // --- col part: argmax of column i over inner rows (via F) ---
    if (i < NINNER) {
        __syncthreads();                          // sb/si reuse safety
        const float* row = F + (size_t)i * SP;
        float best = -1.0f; int bidx = 0;
        for (int r = tid; r < NINNER; r += 256) {
            const float q = row[r] * wup[r].x;
            if (q > best) { best = q; bidx = r; }
        }
#pragma unroll
        for (int m = 1; m < 64; m <<= 1) {
            const float ob = __shfl_xor(best, m, 64);
            const int   oi = __shfl_xor(bidx, m, 64);
            if (ob > best || (ob == best && oi < bidx)) { best = ob; bidx = oi; }
        }
        if (lane == 0) { sb[wid] = best; si[wid] = bidx; }
        __syncthreads();
        if (tid == 0) {
            for (int k = 1; k < 4; ++k)
                if (sb[k] > best || (sb[k] == best && si[k] < bidx)) { best = sb[k]; bidx = si[k]; }
            idx1[i] = bidx;
        }
    }
}

// ---------------- K5a/K5b: mutual matching ----------------
__global__ __launch_bounds__(256) void k_match0(const float* __restrict__ max0,
                                                const int* __restrict__ idx0,
                                                const int* __restrict__ idx1,
                                                float* __restrict__ ms0,
                                                int* __restrict__ vld0,
                                                float* __restrict__ out) {
    const int i = blockIdx.x * 256 + threadIdx.x;
    if (i >= NINNER) return;
    const int j = idx0[i];
    const bool mut = (idx1[j] == i);
    const float ms = mut ? max0[i] : 0.0f;
    const bool val = mut && (ms > 0.2f);
    ms0[i] = ms; vld0[i] = val ? 1 : 0;
    out[OOFF_I0 + i] = val ? (float)j : -1.0f;
    out[OOFF_S0 + i] = ms;
}
__global__ __launch_bounds__(256) void k_match1(const int* __restrict__ idx0,
                                                const int* __restrict__ idx1,
                                                const float* __restrict__ ms0,
                                                const int* __restrict__ vld0,
                                                float* __restrict__ out) {
    const int j = blockIdx.x * 256 + threadIdx.x;
    if (j >= NINNER) return;
    const int i = idx1[j];
    const bool mut = (idx0[i] == j);
    const float ms = mut ? ms0[i] : 0.0f;
    const bool val = mut && (vld0[i] != 0);
    out[OOFF_I1 + j] = val ? (float)i : -1.0f;
    out[OOFF_S1 + j] = ms;
}

// ---------------- host ----------------
extern "C" void kernel_launch(void* const* d_in, const int* in_sizes, int n_in,
                              void* d_out, int out_size, void* d_ws, size_t ws_size,
                              hipStream_t stream) {
    const float* A     = (const float*)d_in[0];   // mdesc0 (1,256,2048)
    const float* Bm    = (const float*)d_in[1];   // mdesc1 (1,256,2048)
    const float* alpha = (const float*)d_in[2];   // bin_score scalar

    float* ws = (float*)d_ws;
    float* E    = ws + OFF_E;
    float* F    = ws + OFF_F;
    u64*   wub  = (u64*)(ws + OFF_WUP);
    u64*   wvb  = (u64*)(ws + OFF_WVP);
    float* max0 = ws + OFF_MAX0;
    int*   idx0 = (int*)(ws + OFF_IDX0);
    int*   idx1 = (int*)(ws + OFF_IDX1);
    float* ms0  = ws + OFF_MS0;
    int*   vld0 = (int*)(ws + OFF_VLD0);
    float* out  = (float*)d_out;

    k_gemm<<<dim3(32, 32), 256, 0, stream>>>(A, Bm, E, F);
    k_init<<<dim3(16), 256, 0, stream>>>(E, F, wvb, alpha);
    k_sinkhorn<<<dim3(NB), NT, 0, stream>>>(E, F, wub, wvb, alpha);
    k_finish<<<dim3(NROW), 256, 0, stream>>>(E, F, (const float2*)wub, (const float2*)wvb,
                                             out, max0, idx0, idx1);
    k_match0<<<dim3(8), 256, 0, stream>>>(max0, idx0, idx1, ms0, vld0, out);
    k_match1<<<dim3(8), 256, 0, stream>>>(idx0, idx1, ms0, vld0, out);
}

// Round 7
// 899.671 us; speedup vs baseline: 2.8124x; 1.0211x over previous
//
#include <hip/hip_runtime.h>
#include <hip/hip_bf16.h>
#include <math.h>

// ---------------- problem constants ----------------
#define D        256
#define NINNER   2048
#define NROW     2049          // 2048 + dustbin
#define SP       2064          // padded row stride (floats), 16B-aligned rows
#define ITERS_N  100
#define EPS_F    0.8f
#define TAU_F    1.02f
#define NB       256           // persistent blocks
#define NT       256           // threads per block

typedef unsigned long long u64;

// pair buffers: u64 slots, (tag<<32)|float_bits, double-buffered by tag parity
#define PSTRIDE  2112u         // pairs per buffer (2048 iter slots + slot 2048 final-only)

// ws layout (in floats)
#define SZ_MAT   (2049u * 2064u)          // 4229136
#define OFF_E    0u
#define OFF_F    SZ_MAT
#define OFF_WUP  (2u * SZ_MAT)                  // u64[2][PSTRIDE] = 4*PSTRIDE floats
#define OFF_WVP  (OFF_WUP + 4u * PSTRIDE)
#define OFF_MAX0 (OFF_WVP + 4u * PSTRIDE)
#define OFF_IDX0 (OFF_MAX0 + 2048u)
#define OFF_IDX1 (OFF_IDX0 + 2048u)
#define OFF_MS0  (OFF_IDX1 + 2048u)
#define OFF_VLD0 (OFF_MS0 + 2048u)

// d_out layout (floats)
#define OOFF_Z   0u
#define OOFF_I0  (2049u * 2049u)          // 4198401
#define OOFF_I1  (OOFF_I0 + 2048u)
#define OOFF_S0  (OOFF_I1 + 2048u)
#define OOFF_S1  (OOFF_S0 + 2048u)

__device__ __forceinline__ float    pair_val(u64 x) { return __uint_as_float((unsigned)x); }
__device__ __forceinline__ unsigned pair_tag(u64 x) { return (unsigned)(x >> 32); }
__device__ __forceinline__ u64 make_pair(float v, unsigned t) {
    return ((u64)t << 32) | (u64)__float_as_uint(v);
}

// ---------------- K1: fp32 GEMM -> E = exp(scores), F = E^T (fused) ----------------
__global__ __launch_bounds__(256) void k_gemm(const float* __restrict__ A,
                                              const float* __restrict__ Bm,
                                              float* __restrict__ E,
                                              float* __restrict__ F) {
    __shared__ float As[8][64];
    __shared__ float Bs[8][64];
    const int tid = threadIdx.x;
    const int tx = tid & 15, ty = tid >> 4;
    const int row0 = blockIdx.y * 64, col0 = blockIdx.x * 64;
    float acc[4][4] = {};
    const int lr = tid >> 6, lc = tid & 63;
    for (int k0 = 0; k0 < D; k0 += 8) {
        As[lr][lc]     = A[(k0 + lr) * NINNER + row0 + lc];
        As[lr + 4][lc] = A[(k0 + lr + 4) * NINNER + row0 + lc];
        Bs[lr][lc]     = Bm[(k0 + lr) * NINNER + col0 + lc];
        Bs[lr + 4][lc] = Bm[(k0 + lr + 4) * NINNER + col0 + lc];
        __syncthreads();
#pragma unroll
        for (int kk = 0; kk < 8; ++kk) {
            const float4 av = *(const float4*)&As[kk][ty * 4];
            const float4 bv = *(const float4*)&Bs[kk][tx * 4];
            const float a_[4] = {av.x, av.y, av.z, av.w};
            const float b_[4] = {bv.x, bv.y, bv.z, bv.w};
#pragma unroll
            for (int r = 0; r < 4; ++r)
#pragma unroll
                for (int c = 0; c < 4; ++c)
                    acc[r][c] = fmaf(a_[r], b_[c], acc[r][c]);
        }
        __syncthreads();
    }
    float o[4][4];
#pragma unroll
    for (int r = 0; r < 4; ++r)
#pragma unroll
        for (int c = 0; c < 4; ++c)
            o[r][c] = expf(acc[r][c] * 0.0625f);
    const int row = row0 + ty * 4, col = col0 + tx * 4;
#pragma unroll
    for (int r = 0; r < 4; ++r)     // E tile
        *(float4*)(E + (size_t)(row + r) * SP + col)
            = make_float4(o[r][0], o[r][1], o[r][2], o[r][3]);
#pragma unroll
    for (int c = 0; c < 4; ++c)     // F tile (transposed)
        *(float4*)(F + (size_t)(col + c) * SP + row)
            = make_float4(o[0][c], o[1][c], o[2][c], o[3][c]);
}

// ---------------- K2: bins for E and F + wv pair init (tag 0) ----------------
__global__ __launch_bounds__(256) void k_init(float* __restrict__ E,
                                              float* __restrict__ F,
                                              u64* __restrict__ wvb0,
                                              const float* __restrict__ alpha) {
    const int t = blockIdx.x * 256 + threadIdx.x;
    const float ea = expf(alpha[0]);
    if (t < NINNER) {
        E[(size_t)t * SP + NINNER] = ea;        // E bin column (for epilogue only)
        F[(size_t)t * SP + NINNER] = ea;        // F bin column
        wvb0[t] = make_pair(1.0f, 0u);          // v0 = 0 -> wv = 1, tag 0
    }
    if (t <= NINNER) {
        E[(size_t)NINNER * SP + t] = ea;        // E bin row (+corner)
        F[(size_t)NINNER * SP + t] = ea;        // F bin row (+corner)
    }
}

// ---------------- masked hot poll + light backoff ----------------
__device__ __forceinline__ void poll8(const u64* buf, int tid, unsigned want, float* w) {
    u64 a[8];
#pragma unroll
    for (int q = 0; q < 8; ++q)
        a[q] = __hip_atomic_load(buf + q * 256 + tid, __ATOMIC_RELAXED, __HIP_MEMORY_SCOPE_AGENT);
    for (;;) {
        unsigned miss = 0u;
#pragma unroll
        for (int q = 0; q < 8; ++q)
            miss |= (pair_tag(a[q]) != want) ? (1u << q) : 0u;
        if (!miss) break;
        __builtin_amdgcn_s_sleep(2);     // ~128 cyc backoff: cut poll-storm contention
#pragma unroll
        for (int q = 0; q < 8; ++q)
            if (miss & (1u << q))
                a[q] = __hip_atomic_load(buf + q * 256 + tid, __ATOMIC_RELAXED, __HIP_MEMORY_SCOPE_AGENT);
    }
#pragma unroll
    for (int q = 0; q < 8; ++q) w[q] = pair_val(a[q]);
}

// ---------------- K3: persistent Sinkhorn — barrier-free tagged dataflow ----------------
// Block b owns rows [8b,8b+8) of E and cols [8b,8b+8) of F in registers.
// wu/wv (inner 2048 only) exchanged as (tag,value) 8B atoms, double-buffered
// by tag parity. DUSTBIN POTENTIALS ARE LOCALLY REPLICATED: every block
// computes the full sums anyway (all-to-all), so (ub, vb) evolve bit-
// identically in every block — no dustbin slot in the hot loop at all.
//   S_i   = dot_i + ea*exp(vb)          (bin column term)
//   S_bin = ea*(sum_j wv_j + exp(vb))   (bin row is constant ea)
// Skew bound < 2 iters per parity buffer => no deadlock; 0xAA poison never
// matches a wanted tag (0..100).
__global__ __launch_bounds__(256, 1) void k_sinkhorn(const float* __restrict__ E,
                                                     const float* __restrict__ F,
                                                     u64* wub, u64* wvb,
                                                     const float* __restrict__ alpha) {
    const int b = blockIdx.x, tid = threadIdx.x;
    const int lane = tid & 63, wid = tid >> 6;
    const int base = b * 8;
    const bool lastb = (b == NB - 1);
    __shared__ float red[2][4][9];

    const float norm = -8.317766166719343f;            // -log(4096)
    const float logbin = 7.624618986159398f + norm;     // log(2048) + norm
    const float ea = expf(alpha[0]);

    float eR[8][8], fR[8][8];
#pragma unroll
    for (int r = 0; r < 8; ++r) {
        const float* rowE = E + (size_t)(base + r) * SP;
        const float* rowF = F + (size_t)(base + r) * SP;
#pragma unroll
        for (int q = 0; q < 8; ++q) {
            eR[r][q] = rowE[q * 256 + tid];
            fR[r][q] = rowF[q * 256 + tid];
        }
    }

    float u = 0.0f, v = 0.0f;              // potentials for row/col base+tid (tid<8)
    float ub = 0.0f, vb = 0.0f;            // dustbin potentials — local replicas
    float eub = 1.0f, evb = 1.0f;          // exp(ub), exp(vb)

    for (int it = 0; it < ITERS_N; ++it) {
        // ---- phase A: consume wv tag it, produce wu tag it+1 ----
        {
            const u64* src = wvb + (size_t)(it & 1) * PSTRIDE;
            u64* dst = wub + (size_t)((it + 1) & 1) * PSTRIDE;
            const unsigned prod = (unsigned)(it + 1);
            float w[8];
            poll8(src, tid, (unsigned)it, w);
            float p[8];
#pragma unroll
            for (int r = 0; r < 8; ++r) {
                float s = 0.0f;
#pragma unroll
                for (int q = 0; q < 8; ++q) s = fmaf(eR[r][q], w[q], s);
                p[r] = s;
            }
            float t = w[0] + w[1] + w[2] + w[3] + w[4] + w[5] + w[6] + w[7];
#pragma unroll
            for (int r = 0; r < 8; ++r) {
                float s = p[r];
#pragma unroll
                for (int m = 1; m < 64; m <<= 1) s += __shfl_xor(s, m, 64);
                if (lane == 0) red[0][wid][r] = s;
            }
#pragma unroll
            for (int m = 1; m < 64; m <<= 1) t += __shfl_xor(t, m, 64);
            if (lane == 0) red[0][wid][8] = t;
            __syncthreads();
            // local dustbin update (every thread, identical result)
            const float tsum = red[0][0][8] + red[0][1][8] + red[0][2][8] + red[0][3][8];
            const float Sbin = ea * (tsum + evb);
            ub = ub + EPS_F * ((logbin - logf(Sbin)) / TAU_F - ub);
            if (tid < 8) {
                const float S = red[0][0][tid] + red[0][1][tid] + red[0][2][tid] + red[0][3][tid]
                              + ea * evb;
                const float unew = (norm - logf(S)) / TAU_F;
                u = u + EPS_F * (unew - u);
                __hip_atomic_store(dst + base + tid, make_pair(expf(u), prod),
                                   __ATOMIC_RELAXED, __HIP_MEMORY_SCOPE_AGENT);
            }
            eub = expf(ub);
        }
        // ---- phase B: consume wu tag it+1, produce wv tag it+1 ----
        {
            const u64* src = wub + (size_t)((it + 1) & 1) * PSTRIDE;
            u64* dst = wvb + (size_t)((it + 1) & 1) * PSTRIDE;
            const unsigned prod = (unsigned)(it + 1);
            float w[8];
            poll8(src, tid, prod, w);
            float p[8];
#pragma unroll
            for (int r = 0; r < 8; ++r) {
                float s = 0.0f;
#pragma unroll
                for (int q = 0; q < 8; ++q) s = fmaf(fR[r][q], w[q], s);
                p[r] = s;
            }
            float t = w[0] + w[1] + w[2] + w[3] + w[4] + w[5] + w[6] + w[7];
#pragma unroll
            for (int r = 0; r < 8; ++r) {
                float s = p[r];
#pragma unroll
                for (int m = 1; m < 64; m <<= 1) s += __shfl_xor(s, m, 64);
                if (lane == 0) red[1][wid][r] = s;
            }
#pragma unroll
            for (int m = 1; m < 64; m <<= 1) t += __shfl_xor(t, m, 64);
            if (lane == 0) red[1][wid][8] = t;
            __syncthreads();
            const float tsum = red[1][0][8] + red[1][1][8] + red[1][2][8] + red[1][3][8];
            const float Tbin = ea * (tsum + eub);
            vb = vb + EPS_F * ((logbin - logf(Tbin)) / TAU_F - vb);
            if (tid < 8) {
                const float T = red[1][0][tid] + red[1][1][tid] + red[1][2][tid] + red[1][3][tid]
                              + ea * eub;
                const float vnew = (norm - logf(T)) / TAU_F;
                v = v + EPS_F * (vnew - v);
                __hip_atomic_store(dst + base + tid, make_pair(expf(v), prod),
                                   __ATOMIC_RELAXED, __HIP_MEMORY_SCOPE_AGENT);
            }
            evb = expf(vb);
        }
    }
    // publish final dustbin scalings once (tag 100 -> parity 0) for the epilogue
    if (lastb && tid == 0) {
        __hip_atomic_store(wub + NINNER, make_pair(eub, (unsigned)ITERS_N),
                           __ATOMIC_RELAXED, __HIP_MEMORY_SCOPE_AGENT);
        __hip_atomic_store(wvb + NINNER, make_pair(evb, (unsigned)ITERS_N),
                           __ATOMIC_RELAXED, __HIP_MEMORY_SCOPE_AGENT);
    }
}

// ---------------- K4: fused epilogue — out0 = exp(Z), row argmax, col argmax ----------
// final wu/wv: tag 100 (even) -> parity-0 buffer halves -> .x of float2 pairs
__global__ __launch_bounds__(256) void k_finish(const float* __restrict__ E,
                                                const float* __restrict__ F,
                                                const float2* __restrict__ wup,
                                                const float2* __restrict__ wvp,
                                                float* __restrict__ out,
                                                float* __restrict__ max0,
                                                int* __restrict__ idx0,
                                                int* __restrict__ idx1) {
    const int i = blockIdx.x;                 // 0..2048
    const int tid = threadIdx.x;
    const int lane = tid & 63, wid = tid >> 6;
    __shared__ float sb[4]; __shared__ int si[4];

    // --- row part: write out row i, argmax over inner cols ---
    {
        const float wui = wup[i].x * 4096.0f;     // * exp(-norm)
        const float* row = E + (size_t)i * SP;
        float best = -1.0f; int bidx = 0;
        for (int j = tid; j < NROW; j += 256) {
            const float val = row[j] * wvp[j].x * wui;
            out[(size_t)i * NROW + j] = val;
            if (j < NINNER && val > best) { best = val; bidx = j; }
        }
        if (i < NINNER) {
#pragma unroll
            for (int m = 1; m < 64; m <<= 1) {
                const float ob = __shfl_xor(best, m, 64);
                const int   oi = __shfl_xor(bidx, m, 64);
                if (ob > best || (ob == best && oi < bidx)) { best = ob; bidx = oi; }
            }
            if (lane == 0) { sb[wid] = best; si[wid] = bidx; }
            __syncthreads();
            if (tid == 0) {
                for (int k = 1; k < 4; ++k)
                    if (sb[k] > best || (sb[k] == best && si[k] < bidx)) { best = sb[k]; bidx = si[k]; }
                max0[i] = best; idx0[i] = bidx;
            }
        }
    }

    // --- col part: argmax of column i over inner rows (via F) ---
    if (i < NINNER) {
        __syncthreads();                          // sb/si reuse safety
        const float* row = F + (size_t)i * SP;
        float best = -1.0f; int bidx = 0;
        for (int r = tid; r < NINNER; r += 256) {
            const float q = row[r] * wup[r].x;
            if (q > best) { best = q; bidx = r; }
        }
#pragma unroll
        for (int m = 1; m < 64; m <<= 1) {
            const float ob = __shfl_xor(best, m, 64);
            const int   oi = __shfl_xor(bidx, m, 64);
            if (ob > best || (ob == best && oi < bidx)) { best = ob; bidx = oi; }
        }
        if (lane == 0) { sb[wid] = best; si[wid] = bidx; }
        __syncthreads();
        if (tid == 0) {
            for (int k = 1; k < 4; ++k)
                if (sb[k] > best || (sb[k] == best && si[k] < bidx)) { best = sb[k]; bidx = si[k]; }
            idx1[i] = bidx;
        }
    }
}

// ---------------- K5a/K5b: mutual matching ----------------
__global__ __launch_bounds__(256) void k_match0(const float* __restrict__ max0,
                                                const int* __restrict__ idx0,
                                                const int* __restrict__ idx1,
                                                float* __restrict__ ms0,
                                                int* __restrict__ vld0,
                                                float* __restrict__ out) {
    const int i = blockIdx.x * 256 + threadIdx.x;
    if (i >= NINNER) return;
    const int j = idx0[i];
    const bool mut = (idx1[j] == i);
    const float ms = mut ? max0[i] : 0.0f;
    const bool val = mut && (ms > 0.2f);
    ms0[i] = ms; vld0[i] = val ? 1 : 0;
    out[OOFF_I0 + i] = val ? (float)j : -1.0f;
    out[OOFF_S0 + i] = ms;
}
__global__ __launch_bounds__(256) void k_match1(const int* __restrict__ idx0,
                                                const int* __restrict__ idx1,
                                                const float* __restrict__ ms0,
                                                const int* __restrict__ vld0,
                                                float* __restrict__ out) {
    const int j = blockIdx.x * 256 + threadIdx.x;
    if (j >= NINNER) return;
    const int i = idx1[j];
    const bool mut = (idx0[i] == j);
    const float ms = mut ? ms0[i] : 0.0f;
    const bool val = mut && (vld0[i] != 0);
    out[OOFF_I1 + j] = val ? (float)i : -1.0f;
    out[OOFF_S1 + j] = ms;
}

// ---------------- host ----------------
extern "C" void kernel_launch(void* const* d_in, const int* in_sizes, int n_in,
                              void* d_out, int out_size, void* d_ws, size_t ws_size,
                              hipStream_t stream) {
    const float* A     = (const float*)d_in[0];   // mdesc0 (1,256,2048)
    const float* Bm    = (const float*)d_in[1];   // mdesc1 (1,256,2048)
    const float* alpha = (const float*)d_in[2];   // bin_score scalar

    float* ws = (float*)d_ws;
    float* E    = ws + OFF_E;
    float* F    = ws + OFF_F;
    u64*   wub  = (u64*)(ws + OFF_WUP);
    u64*   wvb  = (u64*)(ws + OFF_WVP);
    float* max0 = ws + OFF_MAX0;
    int*   idx0 = (int*)(ws + OFF_IDX0);
    int*   idx1 = (int*)(ws + OFF_IDX1);
    float* ms0  = ws + OFF_MS0;
    int*   vld0 = (int*)(ws + OFF_VLD0);
    float* out  = (float*)d_out;

    k_gemm<<<dim3(32, 32), 256, 0, stream>>>(A, Bm, E, F);
    k_init<<<dim3(16), 256, 0, stream>>>(E, F, wvb, alpha);
    k_sinkhorn<<<dim3(NB), NT, 0, stream>>>(E, F, wub, wvb, alpha);
    k_finish<<<dim3(NROW), 256, 0, stream>>>(E, F, (const float2*)wub, (const float2*)wvb,
                                             out, max0, idx0, idx1);
    k_match0<<<dim3(8), 256, 0, stream>>>(max0, idx0, idx1, ms0, vld0, out);
    k_match1<<<dim3(8), 256, 0, stream>>>(idx0, idx1, ms0, vld0, out);
}